// Round 1
// baseline (1575.096 us; speedup 1.0000x reference)
//
#include <hip/hip_runtime.h>

typedef unsigned short u16;
typedef __attribute__((ext_vector_type(8))) short short8;
typedef __attribute__((ext_vector_type(4))) float f4;
typedef __attribute__((ext_vector_type(4))) unsigned short u16x4;

__device__ __forceinline__ float b2f(u16 u) {
    unsigned int x = ((unsigned int)u) << 16;
    return __builtin_bit_cast(float, x);
}
__device__ __forceinline__ u16 f2b(float f) {
    unsigned int u = __builtin_bit_cast(unsigned int, f);
    u += 0x7FFFu + ((u >> 16) & 1u);   // round-to-nearest-even
    return (u16)(u >> 16);
}

// ---------------------------------------------------------------------------
// Generic bf16 MFMA GEMM:  C[M,N] = A[M,K] @ Bt[N,K]^T   (+bias, +relu)
// A: bf16 (ASRC=0) or f32 converted on stage (ASRC=1). Bt always bf16.
// C: f32 (CBF=0) or bf16 (CBF=1). Batched via blockIdx.z (bb=z/batchH, hh=z%batchH).
// Tile BM=FM*32, BN=FN*32, BK=32. 4 waves (2x2), wave tile (FM*16)x(FN*16)... x? ->
// wave computes FM x FN fragments of 16x16, i.e. 64x64 for FM=FN=4.
// LDS row stride 72 u16 = 144B: 16B-aligned, spreads 16 rows over 8 bank-slots (2-way, free).
// ---------------------------------------------------------------------------
template<int FM, int FN, int ASRC, int CBF, int EPI>
__global__ __launch_bounds__(256, 2)
void gemm_bt(const void* __restrict__ Ap, const u16* __restrict__ Bp,
             void* __restrict__ Cp, const float* __restrict__ bias,
             int M, int N, int K, int lda, int ldb, int ldc,
             long long sAh, long long sAb, long long sBh, long long sBb,
             long long sCh, long long sCb, int batchH)
{
    constexpr int BM = FM * 32;
    constexpr int BN = FN * 32;
    constexpr int LK = 72;
    __shared__ __align__(16) u16 As[BM * LK];
    __shared__ __align__(16) u16 Bs[BN * LK];

    const int tid  = threadIdx.x;
    const int z    = blockIdx.z;
    const int bb   = z / batchH;
    const int hh   = z - bb * batchH;
    const int m0   = blockIdx.y * BM;
    const int n0   = blockIdx.x * BN;
    const int w    = tid >> 6;
    const int lane = tid & 63;
    const int wr   = w >> 1;
    const int wc   = w & 1;
    const int lrow = lane & 15;
    const int lk   = (lane >> 4) << 3;

    const u16* Bg = Bp + sBb * bb + sBh * hh;

    f4 acc[FM][FN] = {};

    const int nKt = K >> 5;
    for (int kt = 0; kt < nKt; ++kt) {
        __syncthreads();
        if (ASRC == 0) {
            const u16* Ag = (const u16*)Ap + sAb * bb + sAh * hh;
            #pragma unroll
            for (int it = 0; it < (BM * 4) / 256; ++it) {
                const int id = it * 256 + tid;
                const int row = id >> 2, ch = id & 3;
                short8 v = *(const short8*)(Ag + (long long)(m0 + row) * lda + (kt << 5) + (ch << 3));
                *(short8*)(&As[row * LK + (ch << 3)]) = v;
            }
        } else {
            const float* Ag = (const float*)Ap + sAb * bb + sAh * hh;
            #pragma unroll
            for (int it = 0; it < (BM * 8) / 256; ++it) {
                const int id = it * 256 + tid;
                const int row = id >> 3, ch = id & 7;
                f4 v = *(const f4*)(Ag + (long long)(m0 + row) * lda + (kt << 5) + (ch << 2));
                u16x4 o4; o4.x = f2b(v.x); o4.y = f2b(v.y); o4.z = f2b(v.z); o4.w = f2b(v.w);
                *(u16x4*)(&As[row * LK + (ch << 2)]) = o4;
            }
        }
        #pragma unroll
        for (int it = 0; it < (BN * 4) / 256; ++it) {
            const int id = it * 256 + tid;
            const int row = id >> 2, ch = id & 3;
            short8 v = *(const short8*)(Bg + (long long)(n0 + row) * ldb + (kt << 5) + (ch << 3));
            *(short8*)(&Bs[row * LK + (ch << 3)]) = v;
        }
        __syncthreads();

        short8 af[FM], bv[FN];
        #pragma unroll
        for (int m = 0; m < FM; ++m)
            af[m] = *(const short8*)(&As[(wr * FM * 16 + m * 16 + lrow) * LK + lk]);
        #pragma unroll
        for (int n = 0; n < FN; ++n)
            bv[n] = *(const short8*)(&Bs[(wc * FN * 16 + n * 16 + lrow) * LK + lk]);
        #pragma unroll
        for (int m = 0; m < FM; ++m)
            #pragma unroll
            for (int n = 0; n < FN; ++n)
                acc[m][n] = __builtin_amdgcn_mfma_f32_16x16x32_bf16(af[m], bv[n], acc[m][n], 0, 0, 0);
    }

    const int crow0 = m0 + wr * FM * 16 + ((lane >> 4) << 2);
    const int ccol0 = n0 + wc * FN * 16 + lrow;
    if (CBF == 0) {
        float* Cg = (float*)Cp + sCb * bb + sCh * hh;
        #pragma unroll
        for (int m = 0; m < FM; ++m) {
            #pragma unroll
            for (int n = 0; n < FN; ++n) {
                const int col = ccol0 + n * 16;
                float bvv = (EPI >= 1) ? bias[col] : 0.f;
                #pragma unroll
                for (int r = 0; r < 4; ++r) {
                    float vv = acc[m][n][r] + bvv;
                    if (EPI == 2) vv = fmaxf(vv, 0.f);
                    Cg[(long long)(crow0 + m * 16 + r) * ldc + col] = vv;
                }
            }
        }
    } else {
        u16* Cg = (u16*)Cp + sCb * bb + sCh * hh;
        #pragma unroll
        for (int m = 0; m < FM; ++m) {
            #pragma unroll
            for (int n = 0; n < FN; ++n) {
                const int col = ccol0 + n * 16;
                float bvv = (EPI >= 1) ? bias[col] : 0.f;
                #pragma unroll
                for (int r = 0; r < 4; ++r) {
                    float vv = acc[m][n][r] + bvv;
                    if (EPI == 2) vv = fmaxf(vv, 0.f);
                    Cg[(long long)(crow0 + m * 16 + r) * ldc + col] = f2b(vv);
                }
            }
        }
    }
}

// ---------------------------------------------------------------------------
// Elementwise / layout kernels
// ---------------------------------------------------------------------------
__global__ void conv_f2b(const float* __restrict__ in, u16* __restrict__ out, long long n4)
{
    long long i = (long long)blockIdx.x * 256 + threadIdx.x;
    if (i >= n4) return;
    f4 v = *(const f4*)(in + i * 4);
    u16x4 o; o.x = f2b(v.x); o.y = f2b(v.y); o.z = f2b(v.z); o.w = f2b(v.w);
    *(u16x4*)(out + i * 4) = o;
}

// new_mem[b] = [mem[b]; tgt[b]]  (f32 to d_out) + bf16 copy for GEMM input
__global__ void concat_mem(const float* __restrict__ mem, const float* __restrict__ tgt,
                           float* __restrict__ nm, u16* __restrict__ cat)
{
    long long i = (long long)blockIdx.x * 256 + threadIdx.x;  // float4 index, 2M total
    long long b = i >> 19;
    int rem = (int)(i & 524287);
    int r = rem >> 8, c4 = rem & 255;
    const float* sp = (r < 1024) ? (mem + ((b << 10) + r) * 1024 + c4 * 4)
                                 : (tgt + ((b << 10) + (r - 1024)) * 1024 + c4 * 4);
    f4 v = *(const f4*)sp;
    *(f4*)(nm + i * 4) = v;
    u16x4 o; o.x = f2b(v.x); o.y = f2b(v.y); o.z = f2b(v.z); o.w = f2b(v.w);
    *(u16x4*)(cat + i * 4) = o;
}

// W[R][C] f32 -> Wt[C][R] bf16
__global__ void transpose_w(const float* __restrict__ W, u16* __restrict__ Wt, int R, int C)
{
    __shared__ float tile[32][33];
    int c0 = blockIdx.x * 32, r0 = blockIdx.y * 32;
    int tx = threadIdx.x, ty = threadIdx.y;
    tile[ty][tx] = W[(long long)(r0 + ty) * C + c0 + tx];
    __syncthreads();
    Wt[(long long)(c0 + ty) * R + r0 + tx] = f2b(tile[tx][ty]);
}

// v[b*K+j][h*64+d] -> vt[((b*16+h)*64+d)][j]
__global__ void transpose_v(const u16* __restrict__ v, u16* __restrict__ vt, int K)
{
    __shared__ u16 tile[32][33];
    int z = blockIdx.z; int b = z >> 4, hh = z & 15;
    int j0 = blockIdx.x * 32, d0 = blockIdx.y * 32;
    int tx = threadIdx.x, ty = threadIdx.y;
    tile[ty][tx] = v[((long long)b * K + j0 + ty) * 1024 + hh * 64 + d0 + tx];
    __syncthreads();
    vt[((long long)((b * 16 + hh) * 64 + d0 + ty)) * K + j0 + tx] = tile[tx][ty];
}

// qw = q + r_w_bias[hd], qr = q + r_r_bias[hd]   (hd = idx % 1024)
__global__ void add_qbias(const u16* __restrict__ q, const float* __restrict__ rwb,
                          const float* __restrict__ rrb, u16* __restrict__ qw, u16* __restrict__ qr)
{
    long long i = (long long)blockIdx.x * 256 + threadIdx.x;  // per 4 elems, 1M total
    int hd = (int)((i * 4) & 1023);
    u16x4 qq = *(const u16x4*)(q + i * 4);
    f4 wv = *(const f4*)(rwb + hd);
    f4 rv = *(const f4*)(rrb + hd);
    u16x4 a, c;
    a.x = f2b(b2f(qq.x) + wv.x); a.y = f2b(b2f(qq.y) + wv.y);
    a.z = f2b(b2f(qq.z) + wv.z); a.w = f2b(b2f(qq.w) + wv.w);
    c.x = f2b(b2f(qq.x) + rv.x); c.y = f2b(b2f(qq.y) + rv.y);
    c.z = f2b(b2f(qq.z) + rv.z); c.w = f2b(b2f(qq.w) + rv.w);
    *(u16x4*)(qw + i * 4) = a;
    *(u16x4*)(qr + i * 4) = c;
}

// Self-attn softmax (in-place over AC in d_out). Row = (b,h,t), K=2048.
// BD = bdt[row][j + 1023 - t] for j <= t+1024; masked j > t+1024 -> prob 0.
__global__ __launch_bounds__(256) void softmax_self(float* __restrict__ probs, const u16* __restrict__ bdt)
{
    const long long row = blockIdx.x;
    const int t = (int)(row & 1023);
    float* pr = probs + row * 2048;
    const u16* bd = bdt + row * 2048;
    const int tid = threadIdx.x;
    const int limit = t + 1024;
    const int off = 1023 - t;
    const int j0 = tid * 8;

    float ar[8];
    *(f4*)(&ar[0]) = *(const f4*)(pr + j0);
    *(f4*)(&ar[4]) = *(const f4*)(pr + j0 + 4);
    float s[8];
    float m = -3e38f;
    #pragma unroll
    for (int i = 0; i < 8; ++i) {
        int j = j0 + i;
        if (j <= limit) {
            float v = (ar[i] + b2f(bd[j + off])) * 0.125f;
            s[i] = v; m = fmaxf(m, v);
        } else s[i] = -3e38f;
    }
    #pragma unroll
    for (int o2 = 32; o2; o2 >>= 1) m = fmaxf(m, __shfl_xor(m, o2));
    __shared__ float rm[4], rs[4];
    int w = tid >> 6, lane = tid & 63;
    if (lane == 0) rm[w] = m;
    __syncthreads();
    m = fmaxf(fmaxf(rm[0], rm[1]), fmaxf(rm[2], rm[3]));
    float sum = 0.f;
    #pragma unroll
    for (int i = 0; i < 8; ++i) {
        int j = j0 + i;
        float p = (j <= limit) ? __expf(s[i] - m) : 0.f;
        s[i] = p; sum += p;
    }
    #pragma unroll
    for (int o2 = 32; o2; o2 >>= 1) sum += __shfl_xor(sum, o2);
    if (lane == 0) rs[w] = sum;
    __syncthreads();
    sum = rs[0] + rs[1] + rs[2] + rs[3];
    const float inv = 1.f / sum;
    f4 o0, o1;
    o0.x = s[0] * inv; o0.y = s[1] * inv; o0.z = s[2] * inv; o0.w = s[3] * inv;
    o1.x = s[4] * inv; o1.y = s[5] * inv; o1.z = s[6] * inv; o1.w = s[7] * inv;
    *(f4*)(pr + j0) = o0;
    *(f4*)(pr + j0 + 4) = o1;
}

// Cross-attn softmax for batch b (in-place over AC). Row = (h,t), K=1024, no mask.
// BD: j<=t -> bdt[h,t][j+1023-t]; j==t+1 -> 0; j>=t+2 -> bdt[h,t+1][j-t-2]
__global__ __launch_bounds__(256) void softmax_cross(float* __restrict__ probs, const u16* __restrict__ bdt, int b)
{
    const int row = blockIdx.x;           // h*1024 + t
    const int t = row & 1023;
    float* pr = probs + ((long long)b * 16384 + row) * 1024;
    const u16* bd0 = bdt + (long long)row * 1024;
    const int tid = threadIdx.x;
    const int j0 = tid * 4;

    float ar[4];
    *(f4*)(&ar[0]) = *(const f4*)(pr + j0);
    float s[4];
    float m = -3e38f;
    #pragma unroll
    for (int i = 0; i < 4; ++i) {
        int j = j0 + i;
        float bdv;
        if (j <= t)          bdv = b2f(bd0[j + 1023 - t]);
        else if (j == t + 1) bdv = 0.f;
        else                 bdv = b2f(bd0[1024 + j - t - 2]);
        float v = (ar[i] + bdv) * 0.125f;
        s[i] = v; m = fmaxf(m, v);
    }
    #pragma unroll
    for (int o2 = 32; o2; o2 >>= 1) m = fmaxf(m, __shfl_xor(m, o2));
    __shared__ float rm[4], rs[4];
    int w = tid >> 6, lane = tid & 63;
    if (lane == 0) rm[w] = m;
    __syncthreads();
    m = fmaxf(fmaxf(rm[0], rm[1]), fmaxf(rm[2], rm[3]));
    float sum = 0.f;
    #pragma unroll
    for (int i = 0; i < 4; ++i) { float p = __expf(s[i] - m); s[i] = p; sum += p; }
    #pragma unroll
    for (int o2 = 32; o2; o2 >>= 1) sum += __shfl_xor(sum, o2);
    if (lane == 0) rs[w] = sum;
    __syncthreads();
    sum = rs[0] + rs[1] + rs[2] + rs[3];
    const float inv = 1.f / sum;
    f4 o0;
    o0.x = s[0] * inv; o0.y = s[1] * inv; o0.z = s[2] * inv; o0.w = s[3] * inv;
    *(f4*)(pr + j0) = o0;
}

// out = LN(x + h) * g + bl ; optional bf16 copy. Row = 1024 f32.
__global__ __launch_bounds__(256) void ln_res(const float* __restrict__ x, const float* __restrict__ h,
                                              const float* __restrict__ g, const float* __restrict__ bl,
                                              float* __restrict__ o32, u16* __restrict__ obf)
{
    const long long row = blockIdx.x;
    const int tid = threadIdx.x;
    const long long base = row * 1024 + tid * 4;
    f4 xa = *(const f4*)(x + base);
    f4 ha = *(const f4*)(h + base);
    float v0 = xa.x + ha.x, v1 = xa.y + ha.y, v2 = xa.z + ha.z, v3 = xa.w + ha.w;
    float lsum = v0 + v1 + v2 + v3;
    float lsq = v0 * v0 + v1 * v1 + v2 * v2 + v3 * v3;
    #pragma unroll
    for (int o2 = 32; o2; o2 >>= 1) { lsum += __shfl_xor(lsum, o2); lsq += __shfl_xor(lsq, o2); }
    __shared__ float r1[4], r2[4];
    int w = tid >> 6, lane = tid & 63;
    if (lane == 0) { r1[w] = lsum; r2[w] = lsq; }
    __syncthreads();
    lsum = r1[0] + r1[1] + r1[2] + r1[3];
    lsq  = r2[0] + r2[1] + r2[2] + r2[3];
    const float mu = lsum * 0.0009765625f;
    const float var = lsq * 0.0009765625f - mu * mu;
    const float rsd = rsqrtf(var + 1e-5f);
    const int c = tid * 4;
    f4 gv = *(const f4*)(g + c);
    f4 bv = *(const f4*)(bl + c);
    f4 y;
    y.x = (v0 - mu) * rsd * gv.x + bv.x;
    y.y = (v1 - mu) * rsd * gv.y + bv.y;
    y.z = (v2 - mu) * rsd * gv.z + bv.z;
    y.w = (v3 - mu) * rsd * gv.w + bv.w;
    *(f4*)(o32 + base) = y;
    if (obf) {
        u16x4 u; u.x = f2b(y.x); u.y = f2b(y.y); u.z = f2b(y.z); u.w = f2b(y.w);
        *(u16x4*)(obf + base) = u;
    }
}

// ---------------------------------------------------------------------------
extern "C" void kernel_launch(void* const* d_in, const int* in_sizes, int n_in,
                              void* d_out, int out_size, void* d_ws, size_t ws_size,
                              hipStream_t stream)
{
    (void)in_sizes; (void)n_in; (void)out_size;
    const float* src  = (const float*)d_in[0];
    const float* tgt  = (const float*)d_in[1];
    const float* mem  = (const float*)d_in[2];
    const float* pos  = (const float*)d_in[3];
    const float* rwb  = (const float*)d_in[4];
    const float* rrb  = (const float*)d_in[5];
    const float* Wq1  = (const float*)d_in[6];
    const float* Wk1  = (const float*)d_in[7];
    const float* Wv1  = (const float*)d_in[8];
    const float* Wr1  = (const float*)d_in[9];
    const float* Wo1  = (const float*)d_in[10];
    const float* ln1g = (const float*)d_in[11];
    const float* ln1b = (const float*)d_in[12];
    const float* Wq2  = (const float*)d_in[13];
    const float* Wk2  = (const float*)d_in[14];
    const float* Wv2  = (const float*)d_in[15];
    const float* Wr2  = (const float*)d_in[16];
    const float* Wo2  = (const float*)d_in[17];
    const float* ln2g = (const float*)d_in[18];
    const float* ln2b = (const float*)d_in[19];
    const float* Wf1  = (const float*)d_in[20];
    const float* bf1  = (const float*)d_in[21];
    const float* Wf2  = (const float*)d_in[22];
    const float* bf2  = (const float*)d_in[23];
    const float* ln3g = (const float*)d_in[24];
    const float* ln3b = (const float*)d_in[25];

    float* outp   = (float*)d_out;            // [4,1024,1024]
    float* newmem = outp + 4194304;           // [4,2048,1024]
    float* selfP  = outp + 12582912;          // [4,16,1024,2048]
    float* interP = outp + 146800640;         // [4,16,1024,1024]

    char* ws = (char*)d_ws;
    size_t off = 0;
    auto alloc = [&](size_t bytes) -> void* {
        void* p = ws + off;
        off = (off + bytes + 255) & ~(size_t)255;
        return p;
    };
    u16*   tgt_bf  = (u16*)alloc(8u << 20);
    u16*   src_bf  = (u16*)alloc(8u << 20);
    u16*   cat_bf  = (u16*)alloc(16u << 20);
    u16*   pos_bf  = (u16*)alloc(4u << 20);
    u16*   Wq1t = (u16*)alloc(2u << 20);
    u16*   Wk1t = (u16*)alloc(2u << 20);
    u16*   Wv1t = (u16*)alloc(2u << 20);
    u16*   Wr1t = (u16*)alloc(2u << 20);
    u16*   Wo1t = (u16*)alloc(2u << 20);
    u16*   Wq2t = (u16*)alloc(2u << 20);
    u16*   Wk2t = (u16*)alloc(2u << 20);
    u16*   Wv2t = (u16*)alloc(2u << 20);
    u16*   Wr2t = (u16*)alloc(2u << 20);
    u16*   Wo2t = (u16*)alloc(2u << 20);
    u16*   Wf1t = (u16*)alloc(8u << 20);
    u16*   Wf2t = (u16*)alloc(8u << 20);
    u16*   qb   = (u16*)alloc(8u << 20);
    u16*   qwb  = (u16*)alloc(8u << 20);
    u16*   qrb  = (u16*)alloc(8u << 20);
    u16*   kb   = (u16*)alloc(16u << 20);
    u16*   vb   = (u16*)alloc(16u << 20);
    u16*   vtb  = (u16*)alloc(16u << 20);
    u16*   ob   = (u16*)alloc(8u << 20);
    float* projb = (float*)alloc(16u << 20);
    u16*   r1b  = (u16*)alloc(4u << 20);
    u16*   r2b  = (u16*)alloc(2u << 20);
    float* out1_32 = (float*)alloc(16u << 20);
    u16*   out1_bf = (u16*)alloc(8u << 20);
    float* out2_32 = (float*)alloc(16u << 20);
    u16*   out2_bf = (u16*)alloc(8u << 20);
    u16*   hb   = (u16*)alloc(32u << 20);
    u16*   bdt2 = (u16*)alloc(32u << 20);
    if (off > ws_size) return;  // workspace too small — fail loudly via absmax

    dim3 tb(32, 32);

    // ---- phase 0: conversions / transposes / new_mem
    concat_mem<<<8192, 256, 0, stream>>>(mem, tgt, newmem, cat_bf);
    conv_f2b<<<4096, 256, 0, stream>>>(tgt, tgt_bf, 1048576);
    conv_f2b<<<4096, 256, 0, stream>>>(src, src_bf, 1048576);
    conv_f2b<<<2048, 256, 0, stream>>>(pos, pos_bf, 524288);
    transpose_w<<<dim3(32, 32), tb, 0, stream>>>(Wq1, Wq1t, 1024, 1024);
    transpose_w<<<dim3(32, 32), tb, 0, stream>>>(Wk1, Wk1t, 1024, 1024);
    transpose_w<<<dim3(32, 32), tb, 0, stream>>>(Wv1, Wv1t, 1024, 1024);
    transpose_w<<<dim3(32, 32), tb, 0, stream>>>(Wr1, Wr1t, 1024, 1024);
    transpose_w<<<dim3(32, 32), tb, 0, stream>>>(Wo1, Wo1t, 1024, 1024);
    transpose_w<<<dim3(32, 32), tb, 0, stream>>>(Wq2, Wq2t, 1024, 1024);
    transpose_w<<<dim3(32, 32), tb, 0, stream>>>(Wk2, Wk2t, 1024, 1024);
    transpose_w<<<dim3(32, 32), tb, 0, stream>>>(Wv2, Wv2t, 1024, 1024);
    transpose_w<<<dim3(32, 32), tb, 0, stream>>>(Wr2, Wr2t, 1024, 1024);
    transpose_w<<<dim3(32, 32), tb, 0, stream>>>(Wo2, Wo2t, 1024, 1024);
    transpose_w<<<dim3(128, 32), tb, 0, stream>>>(Wf1, Wf1t, 1024, 4096);
    transpose_w<<<dim3(32, 128), tb, 0, stream>>>(Wf2, Wf2t, 4096, 1024);

    // ---- layer 1: self relative attention (K=2048)
    gemm_bt<4,4,0,1,0><<<dim3(8,32,1), 256, 0, stream>>>(tgt_bf, Wq1t, qb, nullptr,
        4096,1024,1024, 1024,1024,1024, 0,0,0,0,0,0, 1);
    gemm_bt<4,4,0,1,0><<<dim3(8,64,1), 256, 0, stream>>>(cat_bf, Wk1t, kb, nullptr,
        8192,1024,1024, 1024,1024,1024, 0,0,0,0,0,0, 1);
    gemm_bt<4,4,0,1,0><<<dim3(8,64,1), 256, 0, stream>>>(cat_bf, Wv1t, vb, nullptr,
        8192,1024,1024, 1024,1024,1024, 0,0,0,0,0,0, 1);
    gemm_bt<4,4,0,1,0><<<dim3(8,16,1), 256, 0, stream>>>(pos_bf, Wr1t, r1b, nullptr,
        2048,1024,1024, 1024,1024,1024, 0,0,0,0,0,0, 1);
    add_qbias<<<4096, 256, 0, stream>>>(qb, rwb, rrb, qwb, qrb);
    // AC -> selfP (f32, raw scores)
    gemm_bt<4,4,0,0,0><<<dim3(16,8,64), 256, 0, stream>>>(qwb, kb, selfP, nullptr,
        1024,2048,64, 1024,1024,2048,
        64LL,1048576LL, 64LL,2097152LL, 2097152LL,33554432LL, 16);
    // BD~ -> interP region reused as bf16 scratch (exact fit)
    gemm_bt<4,4,0,1,0><<<dim3(16,8,64), 256, 0, stream>>>(qrb, r1b, (void*)interP, nullptr,
        1024,2048,64, 1024,1024,2048,
        64LL,1048576LL, 64LL,0LL, 2097152LL,33554432LL, 16);
    softmax_self<<<65536, 256, 0, stream>>>(selfP, (const u16*)interP);
    transpose_v<<<dim3(64,2,64), tb, 0, stream>>>(vb, vtb, 2048);
    // PV: A = probs (f32), out bf16 o
    gemm_bt<4,2,1,1,0><<<dim3(1,8,64), 256, 0, stream>>>(selfP, vtb, ob, nullptr,
        1024,64,2048, 2048,2048,1024,
        2097152LL,33554432LL, 131072LL,2097152LL, 64LL,1048576LL, 16);
    gemm_bt<4,4,0,0,0><<<dim3(8,32,1), 256, 0, stream>>>(ob, Wo1t, projb, nullptr,
        4096,1024,1024, 1024,1024,1024, 0,0,0,0,0,0, 1);
    ln_res<<<4096, 256, 0, stream>>>(tgt, projb, ln1g, ln1b, out1_32, out1_bf);

    // ---- layer 2: cross relative attention (K=1024, no mask)
    gemm_bt<4,4,0,1,0><<<dim3(8,32,1), 256, 0, stream>>>(out1_bf, Wq2t, qb, nullptr,
        4096,1024,1024, 1024,1024,1024, 0,0,0,0,0,0, 1);
    gemm_bt<4,4,0,1,0><<<dim3(8,32,1), 256, 0, stream>>>(src_bf, Wk2t, kb, nullptr,
        4096,1024,1024, 1024,1024,1024, 0,0,0,0,0,0, 1);
    gemm_bt<4,4,0,1,0><<<dim3(8,32,1), 256, 0, stream>>>(src_bf, Wv2t, vb, nullptr,
        4096,1024,1024, 1024,1024,1024, 0,0,0,0,0,0, 1);
    gemm_bt<4,4,0,1,0><<<dim3(8,8,1), 256, 0, stream>>>(pos_bf + 1048576, Wr2t, r2b, nullptr,
        1024,1024,1024, 1024,1024,1024, 0,0,0,0,0,0, 1);
    add_qbias<<<4096, 256, 0, stream>>>(qb, rwb, rrb, qwb, qrb);
    gemm_bt<4,4,0,0,0><<<dim3(8,8,64), 256, 0, stream>>>(qwb, kb, interP, nullptr,
        1024,1024,64, 1024,1024,1024,
        64LL,1048576LL, 64LL,1048576LL, 1048576LL,16777216LL, 16);
    for (int b2 = 0; b2 < 4; ++b2) {
        gemm_bt<4,4,0,1,0><<<dim3(8,8,16), 256, 0, stream>>>(qrb + (long long)b2 * 1048576, r2b, bdt2, nullptr,
            1024,1024,64, 1024,1024,1024,
            64LL,0LL, 64LL,0LL, 1048576LL,0LL, 16);
        softmax_cross<<<16384, 256, 0, stream>>>(interP, bdt2, b2);
    }
    transpose_v<<<dim3(32,2,64), tb, 0, stream>>>(vb, vtb, 1024);
    gemm_bt<4,2,1,1,0><<<dim3(1,8,64), 256, 0, stream>>>(interP, vtb, ob, nullptr,
        1024,64,1024, 1024,1024,1024,
        1048576LL,16777216LL, 65536LL,1048576LL, 64LL,1048576LL, 16);
    gemm_bt<4,4,0,0,0><<<dim3(8,32,1), 256, 0, stream>>>(ob, Wo2t, projb, nullptr,
        4096,1024,1024, 1024,1024,1024, 0,0,0,0,0,0, 1);
    ln_res<<<4096, 256, 0, stream>>>(out1_32, projb, ln2g, ln2b, out2_32, out2_bf);

    // ---- layer 3: FF
    gemm_bt<4,4,0,1,2><<<dim3(32,32,1), 256, 0, stream>>>(out2_bf, Wf1t, hb, bf1,
        4096,4096,1024, 1024,1024,4096, 0,0,0,0,0,0, 1);
    gemm_bt<4,4,0,0,1><<<dim3(8,32,1), 256, 0, stream>>>(hb, Wf2t, projb, bf2,
        4096,1024,4096, 4096,4096,1024, 0,0,0,0,0,0, 1);
    ln_res<<<4096, 256, 0, stream>>>(out2_32, projb, ln3g, ln3b, outp, nullptr);
}

// Round 2
// 1542.179 us; speedup vs baseline: 1.0213x; 1.0213x over previous
//
#include <hip/hip_runtime.h>

typedef unsigned short u16;
typedef __attribute__((ext_vector_type(8))) short short8;
typedef __attribute__((ext_vector_type(4))) float f4;
typedef __attribute__((ext_vector_type(4))) unsigned short u16x4;

__device__ __forceinline__ float b2f(u16 u) {
    unsigned int x = ((unsigned int)u) << 16;
    return __builtin_bit_cast(float, x);
}
__device__ __forceinline__ u16 f2b(float f) {
    unsigned int u = __builtin_bit_cast(unsigned int, f);
    u += 0x7FFFu + ((u >> 16) & 1u);   // round-to-nearest-even
    return (u16)(u >> 16);
}

__device__ __forceinline__ void gl16(const void* g, void* l) {
    __builtin_amdgcn_global_load_lds(
        (const __attribute__((address_space(1))) void*)g,
        (__attribute__((address_space(3))) void*)l, 16, 0, 0);
}

// ---------------------------------------------------------------------------
// bf16 MFMA GEMM with global_load_lds staging (m97 structure):
//   C[M,N] = A[M,K] @ Bt[N,K]^T  (+bias, +relu)
// Tile 128x128, BK=32, 4 waves (2x2), each wave 64x64 (4x4 fragments 16x16).
// LDS linear [rows][32] u16 (no pad — required by global_load_lds).
// CBF: 0 f32-out, 1 bf16-out. EPI: 0 none, 1 +bias, 2 +bias+relu.
// SHIFT (CBF=1 only): 0 none, 1 self rel-shift write, 2 cross rel-shift write.
// ---------------------------------------------------------------------------
template<int FM, int FN, int CBF, int EPI, int SHIFT>
__global__ __launch_bounds__(256, 3)
void gemm_bt(const u16* __restrict__ Ap, const u16* __restrict__ Bp,
             void* __restrict__ Cp, const float* __restrict__ bias,
             int M, int N, int K, int lda, int ldb, int ldc,
             long long sAh, long long sAb, long long sBh, long long sBb,
             long long sCh, long long sCb, int batchH)
{
    constexpr int BM = FM * 32;
    constexpr int BN = FN * 32;
    __shared__ __align__(16) u16 As[BM * 32];
    __shared__ __align__(16) u16 Bs[BN * 32];

    const int tid  = threadIdx.x;
    const int z    = blockIdx.z;
    const int bb   = z / batchH;
    const int hh   = z - bb * batchH;
    const int m0   = blockIdx.y * BM;
    const int n0   = blockIdx.x * BN;
    const int w    = tid >> 6;
    const int lane = tid & 63;
    const int wr   = w >> 1;
    const int wc   = w & 1;
    const int lrow = lane & 15;
    const int lk   = (lane >> 4) << 3;
    const int lrow4 = lane >> 2;       // staging: row within 16-row chunk
    const int lch   = lane & 3;        // staging: 16B chunk within row

    const u16* Ag = Ap + sAb * bb + sAh * hh;
    const u16* Bg = Bp + sBb * bb + sBh * hh;

    f4 acc[FM][FN] = {};

    const int nKt = K >> 5;
    for (int kt = 0; kt < nKt; ++kt) {
        const int kb = kt << 5;
        __syncthreads();
        #pragma unroll
        for (int i = 0; i < BM / 64; ++i) {
            const int row0 = (w + i * 4) << 4;
            gl16(Ag + (long long)(m0 + row0 + lrow4) * lda + kb + (lch << 3),
                 &As[row0 * 32]);
        }
        #pragma unroll
        for (int i = 0; i < BN / 64; ++i) {
            const int row0 = (w + i * 4) << 4;
            gl16(Bg + (long long)(n0 + row0 + lrow4) * ldb + kb + (lch << 3),
                 &Bs[row0 * 32]);
        }
        __syncthreads();

        short8 af[FM], bv[FN];
        #pragma unroll
        for (int m = 0; m < FM; ++m)
            af[m] = *(const short8*)(&As[(wr * FM * 16 + m * 16 + lrow) * 32 + lk]);
        #pragma unroll
        for (int n = 0; n < FN; ++n)
            bv[n] = *(const short8*)(&Bs[(wc * FN * 16 + n * 16 + lrow) * 32 + lk]);
        #pragma unroll
        for (int m = 0; m < FM; ++m)
            #pragma unroll
            for (int n = 0; n < FN; ++n)
                acc[m][n] = __builtin_amdgcn_mfma_f32_16x16x32_bf16(af[m], bv[n], acc[m][n], 0, 0, 0);
    }

    const int crow0 = m0 + wr * FM * 16 + ((lane >> 4) << 2);
    const int ccol0 = n0 + wc * FN * 16 + lrow;
    if (CBF == 0) {
        float* Cg = (float*)Cp + sCb * bb + sCh * hh;
        #pragma unroll
        for (int m = 0; m < FM; ++m) {
            #pragma unroll
            for (int n = 0; n < FN; ++n) {
                const int col = ccol0 + n * 16;
                float bvv = (EPI >= 1) ? bias[col] : 0.f;
                #pragma unroll
                for (int r = 0; r < 4; ++r) {
                    float vv = acc[m][n][r] + bvv;
                    if (EPI == 2) vv = fmaxf(vv, 0.f);
                    Cg[(long long)(crow0 + m * 16 + r) * ldc + col] = vv;
                }
            }
        }
    } else {
        u16* Cg = (u16*)Cp + sCb * bb + sCh * hh;
        #pragma unroll
        for (int m = 0; m < FM; ++m) {
            #pragma unroll
            for (int n = 0; n < FN; ++n) {
                const int col = ccol0 + n * 16;
                float bvv = (EPI >= 1) ? bias[col] : 0.f;
                #pragma unroll
                for (int r = 0; r < 4; ++r) {
                    float vv = acc[m][n][r] + bvv;
                    if (EPI == 2) vv = fmaxf(vv, 0.f);
                    const int t = crow0 + m * 16 + r;
                    if (SHIFT == 0) {
                        Cg[(long long)t * ldc + col] = f2b(vv);
                    } else if (SHIFT == 1) {
                        const int j = col + t - 1023;
                        if (j >= 0 && j < 2048) Cg[(long long)t * ldc + j] = f2b(vv);
                    } else {
                        const int j1 = col + t - 1023;
                        if (j1 >= 0) Cg[(long long)t * ldc + j1] = f2b(vv);
                        const int j2 = col + t + 1;
                        if (t >= 1 && j2 < 1024) Cg[(long long)(t - 1) * ldc + j2] = f2b(vv);
                    }
                }
            }
        }
    }
}

// ---------------------------------------------------------------------------
// Fused softmax + probs-write + PV, self layer.
// Block: 32 q-rows of one (b,h); 512 threads (8 waves).
// scores f32 in-place in probs; bds = shifted BD~ bf16; vt = V^T [bh*64+d][2048].
// ---------------------------------------------------------------------------
__global__ __launch_bounds__(512) void smpv_self(float* __restrict__ probs,
        const u16* __restrict__ bds, const u16* __restrict__ vt, u16* __restrict__ ob)
{
    __shared__ __align__(16) u16 e[32][2056];
    __shared__ float rinv[32];
    const int tid = threadIdx.x;
    const int bh  = blockIdx.y;
    const int t0  = blockIdx.x << 5;
    const int r   = tid >> 4;
    const int q   = tid & 15;
    const int t   = t0 + r;
    const int limit = t + 1024;           // j <= limit valid (causal)
    float* pr = probs + ((long long)bh * 1024 + t) * 2048;
    const u16* bd = bds + ((long long)bh * 1024 + t) * 2048;

    float mx = -3e38f;
    #pragma unroll 4
    for (int i = 0; i < 16; ++i) {
        const int j0 = q * 8 + i * 128;
        f4 a0 = *(const f4*)(pr + j0);
        f4 a1 = *(const f4*)(pr + j0 + 4);
        short8 b8 = *(const short8*)(bd + j0);
        float sv[8] = {a0.x, a0.y, a0.z, a0.w, a1.x, a1.y, a1.z, a1.w};
        short8 st;
        #pragma unroll
        for (int k = 0; k < 8; ++k) {
            float v = (sv[k] + b2f((u16)b8[k])) * 0.125f;
            u16 vb;
            if (j0 + k <= limit) { vb = f2b(v); mx = fmaxf(mx, b2f(vb)); }
            else vb = 0xFF80u;            // -inf bf16
            st[k] = (short)vb;
        }
        *(short8*)&e[r][j0] = st;
    }
    #pragma unroll
    for (int o = 1; o < 16; o <<= 1) mx = fmaxf(mx, __shfl_xor(mx, o));

    float sum = 0.f;
    #pragma unroll 4
    for (int i = 0; i < 16; ++i) {
        const int j0 = q * 8 + i * 128;
        short8 s8 = *(const short8*)&e[r][j0];
        short8 st;
        #pragma unroll
        for (int k = 0; k < 8; ++k) {
            float ev = __expf(b2f((u16)s8[k]) - mx);   // masked: exp(-inf)=0
            sum += ev;
            st[k] = (short)f2b(ev);
        }
        *(short8*)&e[r][j0] = st;
    }
    #pragma unroll
    for (int o = 1; o < 16; o <<= 1) sum += __shfl_xor(sum, o);
    const float inv = 1.f / sum;
    if (q == 0) rinv[r] = inv;

    #pragma unroll 4
    for (int i = 0; i < 16; ++i) {
        const int j0 = q * 8 + i * 128;
        short8 e8 = *(const short8*)&e[r][j0];
        f4 p0, p1;
        p0.x = b2f((u16)e8[0]) * inv; p0.y = b2f((u16)e8[1]) * inv;
        p0.z = b2f((u16)e8[2]) * inv; p0.w = b2f((u16)e8[3]) * inv;
        p1.x = b2f((u16)e8[4]) * inv; p1.y = b2f((u16)e8[5]) * inv;
        p1.z = b2f((u16)e8[6]) * inv; p1.w = b2f((u16)e8[7]) * inv;
        *(f4*)(pr + j0) = p0;
        *(f4*)(pr + j0 + 4) = p1;
    }
    __syncthreads();

    // PV: 8 waves = 2 row-blocks x 4 d-blocks of 16x16 output
    const int w = tid >> 6, lane = tid & 63;
    const int rb = w >> 2, db = (w & 3) << 4;
    const u16* vrow = vt + ((long long)bh * 64 + db + (lane & 15)) * 2048 + ((lane >> 4) << 3);
    f4 acc = {};
    #pragma unroll 8
    for (int kc = 0; kc < 64; ++kc) {
        short8 a = *(const short8*)&e[rb * 16 + (lane & 15)][kc * 32 + ((lane >> 4) << 3)];
        short8 b = *(const short8*)(vrow + kc * 32);
        acc = __builtin_amdgcn_mfma_f32_16x16x32_bf16(a, b, acc, 0, 0, 0);
    }
    const int b_ = bh >> 4, h_ = bh & 15;
    const int orow = (lane >> 4) << 2;
    const int d = db + (lane & 15);
    u16* obase = ob + ((long long)(b_ * 1024 + t0 + rb * 16 + orow)) * 1024 + h_ * 64 + d;
    #pragma unroll
    for (int rr = 0; rr < 4; ++rr) {
        float val = acc[rr] * rinv[rb * 16 + orow + rr];
        obase[(long long)rr * 1024] = f2b(val);
    }
}

// ---------------------------------------------------------------------------
// Fused softmax + probs-write + PV, cross layer (per batch). K=1024, no mask.
// bds row t: col j<=t and j>=t+2 valid (shifted dual-write); j==t+1 -> 0.
// ---------------------------------------------------------------------------
__global__ __launch_bounds__(512) void smpv_cross(float* __restrict__ probs,
        const u16* __restrict__ bds, const u16* __restrict__ vt, u16* __restrict__ ob, int bsel)
{
    __shared__ __align__(16) u16 e[32][1032];
    __shared__ float rinv[32];
    const int tid = threadIdx.x;
    const int h   = blockIdx.y;
    const int t0  = blockIdx.x << 5;
    const int r   = tid >> 4;
    const int q   = tid & 15;
    const int t   = t0 + r;
    float* pr = probs + ((long long)h * 1024 + t) * 1024;
    const u16* bd = bds + ((long long)h * 1024 + t) * 1024;

    float mx = -3e38f;
    #pragma unroll 4
    for (int i = 0; i < 8; ++i) {
        const int j0 = q * 8 + i * 128;
        f4 a0 = *(const f4*)(pr + j0);
        f4 a1 = *(const f4*)(pr + j0 + 4);
        short8 b8 = *(const short8*)(bd + j0);
        float sv[8] = {a0.x, a0.y, a0.z, a0.w, a1.x, a1.y, a1.z, a1.w};
        short8 st;
        #pragma unroll
        for (int k = 0; k < 8; ++k) {
            float bdv = b2f((u16)b8[k]);
            if (j0 + k == t + 1) bdv = 0.f;
            float v = (sv[k] + bdv) * 0.125f;
            u16 vb = f2b(v);
            mx = fmaxf(mx, b2f(vb));
            st[k] = (short)vb;
        }
        *(short8*)&e[r][j0] = st;
    }
    #pragma unroll
    for (int o = 1; o < 16; o <<= 1) mx = fmaxf(mx, __shfl_xor(mx, o));

    float sum = 0.f;
    #pragma unroll 4
    for (int i = 0; i < 8; ++i) {
        const int j0 = q * 8 + i * 128;
        short8 s8 = *(const short8*)&e[r][j0];
        short8 st;
        #pragma unroll
        for (int k = 0; k < 8; ++k) {
            float ev = __expf(b2f((u16)s8[k]) - mx);
            sum += ev;
            st[k] = (short)f2b(ev);
        }
        *(short8*)&e[r][j0] = st;
    }
    #pragma unroll
    for (int o = 1; o < 16; o <<= 1) sum += __shfl_xor(sum, o);
    const float inv = 1.f / sum;
    if (q == 0) rinv[r] = inv;

    #pragma unroll 4
    for (int i = 0; i < 8; ++i) {
        const int j0 = q * 8 + i * 128;
        short8 e8 = *(const short8*)&e[r][j0];
        f4 p0, p1;
        p0.x = b2f((u16)e8[0]) * inv; p0.y = b2f((u16)e8[1]) * inv;
        p0.z = b2f((u16)e8[2]) * inv; p0.w = b2f((u16)e8[3]) * inv;
        p1.x = b2f((u16)e8[4]) * inv; p1.y = b2f((u16)e8[5]) * inv;
        p1.z = b2f((u16)e8[6]) * inv; p1.w = b2f((u16)e8[7]) * inv;
        *(f4*)(pr + j0) = p0;
        *(f4*)(pr + j0 + 4) = p1;
    }
    __syncthreads();

    const int w = tid >> 6, lane = tid & 63;
    const int rb = w >> 2, db = (w & 3) << 4;
    const u16* vrow = vt + ((long long)((bsel * 16 + h) * 64 + db + (lane & 15))) * 1024 + ((lane >> 4) << 3);
    f4 acc = {};
    #pragma unroll 8
    for (int kc = 0; kc < 32; ++kc) {
        short8 a = *(const short8*)&e[rb * 16 + (lane & 15)][kc * 32 + ((lane >> 4) << 3)];
        short8 b = *(const short8*)(vrow + kc * 32);
        acc = __builtin_amdgcn_mfma_f32_16x16x32_bf16(a, b, acc, 0, 0, 0);
    }
    const int orow = (lane >> 4) << 2;
    const int d = db + (lane & 15);
    u16* obase = ob + ((long long)(bsel * 1024 + t0 + rb * 16 + orow)) * 1024 + h * 64 + d;
    #pragma unroll
    for (int rr = 0; rr < 4; ++rr) {
        float val = acc[rr] * rinv[rb * 16 + orow + rr];
        obase[(long long)rr * 1024] = f2b(val);
    }
}

// ---------------------------------------------------------------------------
// Elementwise / layout kernels
// ---------------------------------------------------------------------------
__global__ void conv_f2b(const float* __restrict__ in, u16* __restrict__ out, long long n4)
{
    long long i = (long long)blockIdx.x * 256 + threadIdx.x;
    if (i >= n4) return;
    f4 v = *(const f4*)(in + i * 4);
    u16x4 o; o.x = f2b(v.x); o.y = f2b(v.y); o.z = f2b(v.z); o.w = f2b(v.w);
    *(u16x4*)(out + i * 4) = o;
}

__global__ void concat_mem(const float* __restrict__ mem, const float* __restrict__ tgt,
                           float* __restrict__ nm, u16* __restrict__ cat)
{
    long long i = (long long)blockIdx.x * 256 + threadIdx.x;
    long long b = i >> 19;
    int rem = (int)(i & 524287);
    int r = rem >> 8, c4 = rem & 255;
    const float* sp = (r < 1024) ? (mem + ((b << 10) + r) * 1024 + c4 * 4)
                                 : (tgt + ((b << 10) + (r - 1024)) * 1024 + c4 * 4);
    f4 v = *(const f4*)sp;
    *(f4*)(nm + i * 4) = v;
    u16x4 o; o.x = f2b(v.x); o.y = f2b(v.y); o.z = f2b(v.z); o.w = f2b(v.w);
    *(u16x4*)(cat + i * 4) = o;
}

__global__ void transpose_w(const float* __restrict__ W, u16* __restrict__ Wt, int R, int C)
{
    __shared__ float tile[32][33];
    int c0 = blockIdx.x * 32, r0 = blockIdx.y * 32;
    int tx = threadIdx.x, ty = threadIdx.y;
    tile[ty][tx] = W[(long long)(r0 + ty) * C + c0 + tx];
    __syncthreads();
    Wt[(long long)(c0 + ty) * R + r0 + tx] = f2b(tile[tx][ty]);
}

__global__ void transpose_v(const u16* __restrict__ v, u16* __restrict__ vt, int K)
{
    __shared__ u16 tile[32][33];
    int z = blockIdx.z; int b = z >> 4, hh = z & 15;
    int j0 = blockIdx.x * 32, d0 = blockIdx.y * 32;
    int tx = threadIdx.x, ty = threadIdx.y;
    tile[ty][tx] = v[((long long)b * K + j0 + ty) * 1024 + hh * 64 + d0 + tx];
    __syncthreads();
    vt[((long long)((b * 16 + hh) * 64 + d0 + ty)) * K + j0 + tx] = tile[tx][ty];
}

__global__ void add_qbias(const u16* __restrict__ q, const float* __restrict__ rwb,
                          const float* __restrict__ rrb, u16* __restrict__ qw, u16* __restrict__ qr)
{
    long long i = (long long)blockIdx.x * 256 + threadIdx.x;
    int hd = (int)((i * 4) & 1023);
    u16x4 qq = *(const u16x4*)(q + i * 4);
    f4 wv = *(const f4*)(rwb + hd);
    f4 rv = *(const f4*)(rrb + hd);
    u16x4 a, c;
    a.x = f2b(b2f(qq.x) + wv.x); a.y = f2b(b2f(qq.y) + wv.y);
    a.z = f2b(b2f(qq.z) + wv.z); a.w = f2b(b2f(qq.w) + wv.w);
    c.x = f2b(b2f(qq.x) + rv.x); c.y = f2b(b2f(qq.y) + rv.y);
    c.z = f2b(b2f(qq.z) + rv.z); c.w = f2b(b2f(qq.w) + rv.w);
    *(u16x4*)(qw + i * 4) = a;
    *(u16x4*)(qr + i * 4) = c;
}

__global__ __launch_bounds__(256) void ln_res(const float* __restrict__ x, const float* __restrict__ h,
                                              const float* __restrict__ g, const float* __restrict__ bl,
                                              float* __restrict__ o32, u16* __restrict__ obf)
{
    const long long row = blockIdx.x;
    const int tid = threadIdx.x;
    const long long base = row * 1024 + tid * 4;
    f4 xa = *(const f4*)(x + base);
    f4 ha = *(const f4*)(h + base);
    float v0 = xa.x + ha.x, v1 = xa.y + ha.y, v2 = xa.z + ha.z, v3 = xa.w + ha.w;
    float lsum = v0 + v1 + v2 + v3;
    float lsq = v0 * v0 + v1 * v1 + v2 * v2 + v3 * v3;
    #pragma unroll
    for (int o2 = 32; o2; o2 >>= 1) { lsum += __shfl_xor(lsum, o2); lsq += __shfl_xor(lsq, o2); }
    __shared__ float r1[4], r2[4];
    int w = tid >> 6, lane = tid & 63;
    if (lane == 0) { r1[w] = lsum; r2[w] = lsq; }
    __syncthreads();
    lsum = r1[0] + r1[1] + r1[2] + r1[3];
    lsq  = r2[0] + r2[1] + r2[2] + r2[3];
    const float mu = lsum * 0.0009765625f;
    const float var = lsq * 0.0009765625f - mu * mu;
    const float rsd = rsqrtf(var + 1e-5f);
    const int c = tid * 4;
    f4 gv = *(const f4*)(g + c);
    f4 bv = *(const f4*)(bl + c);
    f4 y;
    y.x = (v0 - mu) * rsd * gv.x + bv.x;
    y.y = (v1 - mu) * rsd * gv.y + bv.y;
    y.z = (v2 - mu) * rsd * gv.z + bv.z;
    y.w = (v3 - mu) * rsd * gv.w + bv.w;
    *(f4*)(o32 + base) = y;
    if (obf) {
        u16x4 u; u.x = f2b(y.x); u.y = f2b(y.y); u.z = f2b(y.z); u.w = f2b(y.w);
        *(u16x4*)(obf + base) = u;
    }
}

// ---------------------------------------------------------------------------
extern "C" void kernel_launch(void* const* d_in, const int* in_sizes, int n_in,
                              void* d_out, int out_size, void* d_ws, size_t ws_size,
                              hipStream_t stream)
{
    (void)in_sizes; (void)n_in; (void)out_size;
    const float* src  = (const float*)d_in[0];
    const float* tgt  = (const float*)d_in[1];
    const float* mem  = (const float*)d_in[2];
    const float* pos  = (const float*)d_in[3];
    const float* rwb  = (const float*)d_in[4];
    const float* rrb  = (const float*)d_in[5];
    const float* Wq1  = (const float*)d_in[6];
    const float* Wk1  = (const float*)d_in[7];
    const float* Wv1  = (const float*)d_in[8];
    const float* Wr1  = (const float*)d_in[9];
    const float* Wo1  = (const float*)d_in[10];
    const float* ln1g = (const float*)d_in[11];
    const float* ln1b = (const float*)d_in[12];
    const float* Wq2  = (const float*)d_in[13];
    const float* Wk2  = (const float*)d_in[14];
    const float* Wv2  = (const float*)d_in[15];
    const float* Wr2  = (const float*)d_in[16];
    const float* Wo2  = (const float*)d_in[17];
    const float* ln2g = (const float*)d_in[18];
    const float* ln2b = (const float*)d_in[19];
    const float* Wf1  = (const float*)d_in[20];
    const float* bf1  = (const float*)d_in[21];
    const float* Wf2  = (const float*)d_in[22];
    const float* bf2  = (const float*)d_in[23];
    const float* ln3g = (const float*)d_in[24];
    const float* ln3b = (const float*)d_in[25];

    float* outp   = (float*)d_out;            // [4,1024,1024]
    float* newmem = outp + 4194304;           // [4,2048,1024]
    float* selfP  = outp + 12582912;          // [4,16,1024,2048]
    float* interP = outp + 146800640;         // [4,16,1024,1024]

    char* ws = (char*)d_ws;
    size_t off = 0;
    auto alloc = [&](size_t bytes) -> void* {
        void* p = ws + off;
        off = (off + bytes + 255) & ~(size_t)255;
        return p;
    };
    u16*   tgt_bf  = (u16*)alloc(8u << 20);
    u16*   src_bf  = (u16*)alloc(8u << 20);
    u16*   cat_bf  = (u16*)alloc(16u << 20);
    u16*   pos_bf  = (u16*)alloc(4u << 20);
    u16*   Wq1t = (u16*)alloc(2u << 20);
    u16*   Wk1t = (u16*)alloc(2u << 20);
    u16*   Wv1t = (u16*)alloc(2u << 20);
    u16*   Wr1t = (u16*)alloc(2u << 20);
    u16*   Wo1t = (u16*)alloc(2u << 20);
    u16*   Wq2t = (u16*)alloc(2u << 20);
    u16*   Wk2t = (u16*)alloc(2u << 20);
    u16*   Wv2t = (u16*)alloc(2u << 20);
    u16*   Wr2t = (u16*)alloc(2u << 20);
    u16*   Wo2t = (u16*)alloc(2u << 20);
    u16*   Wf1t = (u16*)alloc(8u << 20);
    u16*   Wf2t = (u16*)alloc(8u << 20);
    u16*   qb   = (u16*)alloc(8u << 20);
    u16*   qwb  = (u16*)alloc(8u << 20);
    u16*   qrb  = (u16*)alloc(8u << 20);
    u16*   kb   = (u16*)alloc(16u << 20);
    u16*   vb   = (u16*)alloc(16u << 20);
    u16*   vtb  = (u16*)alloc(16u << 20);
    u16*   ob   = (u16*)alloc(8u << 20);
    float* projb = (float*)alloc(16u << 20);
    u16*   r1b  = (u16*)alloc(4u << 20);
    u16*   r2b  = (u16*)alloc(2u << 20);
    float* out1_32 = (float*)alloc(16u << 20);
    u16*   out1_bf = (u16*)alloc(8u << 20);
    float* out2_32 = (float*)alloc(16u << 20);
    u16*   out2_bf = (u16*)alloc(8u << 20);
    u16*   hb   = (u16*)alloc(32u << 20);
    u16*   bdt2 = (u16*)alloc(32u << 20);
    if (off > ws_size) return;

    dim3 tb(32, 32);

    // ---- phase 0: conversions / transposes / new_mem
    concat_mem<<<8192, 256, 0, stream>>>(mem, tgt, newmem, cat_bf);
    conv_f2b<<<4096, 256, 0, stream>>>(tgt, tgt_bf, 1048576);
    conv_f2b<<<4096, 256, 0, stream>>>(src, src_bf, 1048576);
    conv_f2b<<<2048, 256, 0, stream>>>(pos, pos_bf, 524288);
    transpose_w<<<dim3(32, 32), tb, 0, stream>>>(Wq1, Wq1t, 1024, 1024);
    transpose_w<<<dim3(32, 32), tb, 0, stream>>>(Wk1, Wk1t, 1024, 1024);
    transpose_w<<<dim3(32, 32), tb, 0, stream>>>(Wv1, Wv1t, 1024, 1024);
    transpose_w<<<dim3(32, 32), tb, 0, stream>>>(Wr1, Wr1t, 1024, 1024);
    transpose_w<<<dim3(32, 32), tb, 0, stream>>>(Wo1, Wo1t, 1024, 1024);
    transpose_w<<<dim3(32, 32), tb, 0, stream>>>(Wq2, Wq2t, 1024, 1024);
    transpose_w<<<dim3(32, 32), tb, 0, stream>>>(Wk2, Wk2t, 1024, 1024);
    transpose_w<<<dim3(32, 32), tb, 0, stream>>>(Wv2, Wv2t, 1024, 1024);
    transpose_w<<<dim3(32, 32), tb, 0, stream>>>(Wr2, Wr2t, 1024, 1024);
    transpose_w<<<dim3(32, 32), tb, 0, stream>>>(Wo2, Wo2t, 1024, 1024);
    transpose_w<<<dim3(128, 32), tb, 0, stream>>>(Wf1, Wf1t, 1024, 4096);
    transpose_w<<<dim3(32, 128), tb, 0, stream>>>(Wf2, Wf2t, 4096, 1024);

    // ---- layer 1: self relative attention (K=2048)
    gemm_bt<4,4,1,0,0><<<dim3(8,32,1), 256, 0, stream>>>(tgt_bf, Wq1t, qb, nullptr,
        4096,1024,1024, 1024,1024,1024, 0,0,0,0,0,0, 1);
    gemm_bt<4,4,1,0,0><<<dim3(8,64,1), 256, 0, stream>>>(cat_bf, Wk1t, kb, nullptr,
        8192,1024,1024, 1024,1024,1024, 0,0,0,0,0,0, 1);
    gemm_bt<4,4,1,0,0><<<dim3(8,64,1), 256, 0, stream>>>(cat_bf, Wv1t, vb, nullptr,
        8192,1024,1024, 1024,1024,1024, 0,0,0,0,0,0, 1);
    gemm_bt<4,4,1,0,0><<<dim3(8,16,1), 256, 0, stream>>>(pos_bf, Wr1t, r1b, nullptr,
        2048,1024,1024, 1024,1024,1024, 0,0,0,0,0,0, 1);
    add_qbias<<<4096, 256, 0, stream>>>(qb, rwb, rrb, qwb, qrb);
    // AC -> selfP (f32 raw scores, in-place softmax later)
    gemm_bt<4,4,0,0,0><<<dim3(16,8,64), 256, 0, stream>>>(qwb, kb, selfP, nullptr,
        1024,2048,64, 1024,1024,2048,
        64LL,1048576LL, 64LL,2097152LL, 2097152LL,33554432LL, 16);
    // BD~ rel-shifted -> interP region (bf16 scratch, exact fit)
    gemm_bt<4,4,1,0,1><<<dim3(16,8,64), 256, 0, stream>>>(qrb, r1b, (void*)interP, nullptr,
        1024,2048,64, 1024,1024,2048,
        64LL,1048576LL, 64LL,0LL, 2097152LL,33554432LL, 16);
    transpose_v<<<dim3(64,2,64), tb, 0, stream>>>(vb, vtb, 2048);
    smpv_self<<<dim3(32,64), 512, 0, stream>>>(selfP, (const u16*)interP, vtb, ob);
    gemm_bt<4,4,0,0,0><<<dim3(8,32,1), 256, 0, stream>>>(ob, Wo1t, projb, nullptr,
        4096,1024,1024, 1024,1024,1024, 0,0,0,0,0,0, 1);
    ln_res<<<4096, 256, 0, stream>>>(tgt, projb, ln1g, ln1b, out1_32, out1_bf);

    // ---- layer 2: cross relative attention (K=1024, no mask)
    gemm_bt<4,4,1,0,0><<<dim3(8,32,1), 256, 0, stream>>>(out1_bf, Wq2t, qb, nullptr,
        4096,1024,1024, 1024,1024,1024, 0,0,0,0,0,0, 1);
    gemm_bt<4,4,1,0,0><<<dim3(8,32,1), 256, 0, stream>>>(src_bf, Wk2t, kb, nullptr,
        4096,1024,1024, 1024,1024,1024, 0,0,0,0,0,0, 1);
    gemm_bt<4,4,1,0,0><<<dim3(8,32,1), 256, 0, stream>>>(src_bf, Wv2t, vb, nullptr,
        4096,1024,1024, 1024,1024,1024, 0,0,0,0,0,0, 1);
    gemm_bt<4,4,1,0,0><<<dim3(8,8,1), 256, 0, stream>>>(pos_bf + 1048576, Wr2t, r2b, nullptr,
        1024,1024,1024, 1024,1024,1024, 0,0,0,0,0,0, 1);
    add_qbias<<<4096, 256, 0, stream>>>(qb, rwb, rrb, qwb, qrb);
    gemm_bt<4,4,0,0,0><<<dim3(8,8,64), 256, 0, stream>>>(qwb, kb, interP, nullptr,
        1024,1024,64, 1024,1024,1024,
        64LL,1048576LL, 64LL,1048576LL, 1048576LL,16777216LL, 16);
    transpose_v<<<dim3(32,2,64), tb, 0, stream>>>(vb, vtb, 1024);
    for (int b2 = 0; b2 < 4; ++b2) {
        gemm_bt<4,4,1,0,2><<<dim3(8,8,16), 256, 0, stream>>>(qrb + (long long)b2 * 1048576, r2b, bdt2, nullptr,
            1024,1024,64, 1024,1024,1024,
            64LL,0LL, 64LL,0LL, 1048576LL,0LL, 16);
        smpv_cross<<<dim3(32,16), 512, 0, stream>>>(interP + (long long)b2 * 16777216,
            bdt2, vtb, ob, b2);
    }
    gemm_bt<4,4,0,0,0><<<dim3(8,32,1), 256, 0, stream>>>(ob, Wo2t, projb, nullptr,
        4096,1024,1024, 1024,1024,1024, 0,0,0,0,0,0, 1);
    ln_res<<<4096, 256, 0, stream>>>(out1_32, projb, ln2g, ln2b, out2_32, out2_bf);

    // ---- layer 3: FF
    gemm_bt<4,4,1,2,0><<<dim3(32,32,1), 256, 0, stream>>>(out2_bf, Wf1t, hb, bf1,
        4096,4096,1024, 1024,1024,4096, 0,0,0,0,0,0, 1);
    gemm_bt<4,4,0,1,0><<<dim3(8,32,1), 256, 0, stream>>>(hb, Wf2t, projb, bf2,
        4096,1024,4096, 4096,4096,1024, 0,0,0,0,0,0, 1);
    ln_res<<<4096, 256, 0, stream>>>(out2_32, projb, ln3g, ln3b, outp, nullptr);
}